// Round 1
// baseline (1209.458 us; speedup 1.0000x reference)
//
#include <hip/hip_runtime.h>
#include <hip/hip_bf16.h>
#include <math.h>

#define DIM_H 2048
#define VOCAB 32000
#define BM 256
#define BN 256
#define BKT 64
#define NT (DIM_H / BKT)   // 32 K-tiles

typedef _Float16 half8v __attribute__((ext_vector_type(8)));
typedef _Float16 half4v __attribute__((ext_vector_type(4)));
typedef float floatx4 __attribute__((ext_vector_type(4)));

__device__ __forceinline__ void async_copy16(void* lds, const void* g) {
  __builtin_amdgcn_global_load_lds(
      (const __attribute__((address_space(1))) void*)g,
      (__attribute__((address_space(3))) void*)lds,
      16, 0, 0);
}

// ---------------- fp32 -> fp16 convert (vectorized x4) ----------------
__global__ void cvt_f32_f16(const float* __restrict__ src, _Float16* __restrict__ dst, long n) {
  long i = ((long)blockIdx.x * blockDim.x + threadIdx.x) * 4;
  if (i + 3 < n) {
    const float4 v = *(const float4*)(src + i);
    half4v h;
    h.x = (_Float16)v.x; h.y = (_Float16)v.y; h.z = (_Float16)v.z; h.w = (_Float16)v.w;
    *(half4v*)(dst + i) = h;
  }
}

// ---------------- fused prep: W1 convert + 4 x converts + target pack ----------------
__global__ void prep(const float* __restrict__ xc, const float* __restrict__ xr,
                     const float* __restrict__ rxc, const float* __restrict__ rxr,
                     const float* __restrict__ W, _Float16* __restrict__ X16,
                     _Float16* __restrict__ W16,
                     const int* __restrict__ tc, const int* __restrict__ tr,
                     int* __restrict__ tgt) {
  const long b = blockIdx.x;
  if (b < 64000) {
    const long i = (b * 256 + threadIdx.x) * 4;
    const float4 v = *(const float4*)(W + i);
    half4v h;
    h.x = (_Float16)v.x; h.y = (_Float16)v.y; h.z = (_Float16)v.z; h.w = (_Float16)v.w;
    *(half4v*)(W16 + i) = h;
  } else if (b < 72192) {
    const long t = ((b - 64000) * 256 + threadIdx.x) * 4;
    const int seg = (int)(t >> 21);
    const long off = t & ((1L << 21) - 1);
    const float* src = seg == 0 ? xc : seg == 1 ? xr : seg == 2 ? rxc : rxr;
    const float4 v = *(const float4*)(src + off);
    half4v h;
    h.x = (_Float16)v.x; h.y = (_Float16)v.y; h.z = (_Float16)v.z; h.w = (_Float16)v.w;
    *(half4v*)(X16 + t) = h;
  } else {
    const int t = (int)(b - 72192) * 256 + threadIdx.x;
    if (t < 2048) tgt[t] = (t < 1024) ? tc[t] : tr[t - 1024];
  }
}

// ---------------- 256x256 8-wave 4-phase pipelined GEMM + online sum-exp ----------------
// X: [2048,2048] f16, W: [32000,2048] f16 (B^T). Grid: 1000 blocks (8 m-tiles x 125 n-tiles),
// XCD-bijective remap so the 8 m-blocks sharing one W-slice live on one XCD's L2.
// Schedule (T3+T4): dbuf LDS, 4 phases/K-tile, raw s_barrier + counted vmcnt(4) (never 0
// in steady state). Stage stream per tile t: B(t+1)h0, B(t+1)h1, A(t+2)h0, A(t+2)h1 --
// A(t) LDS is fully register-loaded by end of ph1 (barrier), so A(t+2) reuses its slots.
// T2 swizzle: LDS[row][slot] holds G[row][slot ^ (row&7)] (inverse-permuted global source,
// linear gload_lds dest); ds_read applies the same XOR -> 16-way conflict -> 2-way (free).
__global__ __launch_bounds__(512, 2)
void gemm_lse(const _Float16* __restrict__ X, const _Float16* __restrict__ W,
              const float* __restrict__ bias, const int* __restrict__ tgt,
              float* __restrict__ sumexp, float* __restrict__ tgtlogit) {
  __shared__ _Float16 sA[2][BM][BKT];   // 64 KiB
  __shared__ _Float16 sB[2][BN][BKT];   // 64 KiB

  const int tid = threadIdx.x;

  // bijective XCD chunking: 1000 blocks = 8 XCDs x 125; m fast within a chunk
  const int lin = blockIdx.x;
  const int nl  = (lin & 7) * 125 + (lin >> 3);
  const int m0  = (nl & 7) << 8;          // token tile base
  const int n0  = (nl >> 3) << 8;         // vocab tile base

  // staging: thread covers row (tid>>3) [+64 for 2nd load], LDS slot tid&7,
  // global chunk = slot ^ (row&7)  [swizzle source permutation]
  const int srow   = tid >> 3;
  const int schunk = (tid & 7) ^ (srow & 7);
  const _Float16* gA = X + (size_t)(m0 + srow) * DIM_H + schunk * 8;
  const _Float16* gB = W + (size_t)(n0 + srow) * DIM_H + schunk * 8;
  _Float16* lA = &sA[0][0][0] + tid * 8;  // wave-uniform base + lane*16B
  _Float16* lB = &sB[0][0][0] + tid * 8;

#define STG_A(buf, tt, h) { \
    const _Float16* g_ = gA + (size_t)((h) * 128) * DIM_H + (tt) * BKT; \
    _Float16* l_ = lA + (buf) * 16384 + (h) * 8192; \
    async_copy16(l_, g_); \
    async_copy16(l_ + 4096, g_ + (size_t)64 * DIM_H); }
#define STG_B(buf, tt, h) { \
    const _Float16* g_ = gB + (size_t)((h) * 128) * DIM_H + (tt) * BKT; \
    _Float16* l_ = lB + (buf) * 16384 + (h) * 8192; \
    async_copy16(l_, g_); \
    async_copy16(l_ + 4096, g_ + (size_t)64 * DIM_H); }

  // 8 waves: 2 (M) x 4 (N); per-wave output 128 x 64
  const int lane = tid & 63;
  const int w   = tid >> 6;
  const int wm  = (w >> 2) * 128;   // 0 / 128
  const int wn  = (w & 3) * 64;     // 0 / 64 / 128 / 192
  const int l15 = lane & 15;
  const int q   = lane >> 4;
  const int key = l15 & 7;
  const int cofs0 = ((q ^ key) & 7) * 8;        // ks=0 swizzled chunk (f16 elems)
  const int cofs1 = (((4 + q) ^ key) & 7) * 8;  // ks=1

  const _Float16* pA = &sA[0][0][0] + (wm + l15) * BKT;
  const _Float16* pB = &sB[0][0][0] + (wn + l15) * BKT;

  floatx4 acc[8][4];
#pragma unroll
  for (int mf = 0; mf < 8; ++mf)
#pragma unroll
    for (int nf = 0; nf < 4; ++nf) acc[mf][nf] = 0.0f;

  // prologue: A(0), B(0), A(1); leave A(1)'s 4 loads in flight
  STG_A(0, 0, 0); STG_A(0, 0, 1);
  STG_B(0, 0, 0); STG_B(0, 0, 1);
  STG_A(1, 1, 0); STG_A(1, 1, 1);
  asm volatile("s_waitcnt vmcnt(4)" ::: "memory");
  __builtin_amdgcn_s_barrier();

  for (int t = 0; t < NT; ++t) {
    const int cur = t & 1;
    const int nxt = cur ^ 1;
    const int cb  = cur * 16384;

    half8v af[8][2], b01[2][2], b23[2][2];

    // ---------- phase 0: read A(mf0-3) + B(nf0-1); stage B(t+1)h0; MFMA q0 ----------
#pragma unroll
    for (int mf = 0; mf < 4; ++mf) {
      af[mf][0] = *(const half8v*)(pA + cb + mf * 1024 + cofs0);
      af[mf][1] = *(const half8v*)(pA + cb + mf * 1024 + cofs1);
    }
#pragma unroll
    for (int nf = 0; nf < 2; ++nf) {
      b01[nf][0] = *(const half8v*)(pB + cb + nf * 1024 + cofs0);
      b01[nf][1] = *(const half8v*)(pB + cb + nf * 1024 + cofs1);
    }
    if (t + 1 < NT) STG_B(nxt, t + 1, 0);
    __builtin_amdgcn_s_barrier();
    asm volatile("s_waitcnt lgkmcnt(0)" ::: "memory");
    __builtin_amdgcn_sched_barrier(0);
    __builtin_amdgcn_s_setprio(1);
#pragma unroll
    for (int mf = 0; mf < 4; ++mf)
#pragma unroll
      for (int nf = 0; nf < 2; ++nf) {
        acc[mf][nf] = __builtin_amdgcn_mfma_f32_16x16x32_f16(af[mf][0], b01[nf][0], acc[mf][nf], 0, 0, 0);
        acc[mf][nf] = __builtin_amdgcn_mfma_f32_16x16x32_f16(af[mf][1], b01[nf][1], acc[mf][nf], 0, 0, 0);
      }
    __builtin_amdgcn_s_setprio(0);
    __builtin_amdgcn_s_barrier();

    // ---------- phase 1: read A(mf4-7); stage B(t+1)h1; MFMA q1 ----------
#pragma unroll
    for (int mf = 4; mf < 8; ++mf) {
      af[mf][0] = *(const half8v*)(pA + cb + mf * 1024 + cofs0);
      af[mf][1] = *(const half8v*)(pA + cb + mf * 1024 + cofs1);
    }
    if (t + 1 < NT) STG_B(nxt, t + 1, 1);
    __builtin_amdgcn_s_barrier();
    asm volatile("s_waitcnt lgkmcnt(0)" ::: "memory");
    __builtin_amdgcn_sched_barrier(0);
    __builtin_amdgcn_s_setprio(1);
#pragma unroll
    for (int mf = 4; mf < 8; ++mf)
#pragma unroll
      for (int nf = 0; nf < 2; ++nf) {
        acc[mf][nf] = __builtin_amdgcn_mfma_f32_16x16x32_f16(af[mf][0], b01[nf][0], acc[mf][nf], 0, 0, 0);
        acc[mf][nf] = __builtin_amdgcn_mfma_f32_16x16x32_f16(af[mf][1], b01[nf][1], acc[mf][nf], 0, 0, 0);
      }
    __builtin_amdgcn_s_setprio(0);
    __builtin_amdgcn_s_barrier();
    // all A(t) LDS reads complete across waves -> A(t)'s slots are free

    // ---------- phase 2: read B(nf2-3); stage A(t+2)h0 (into A(t)'s slots); MFMA q2 ----------
#pragma unroll
    for (int nf = 0; nf < 2; ++nf) {
      b23[nf][0] = *(const half8v*)(pB + cb + (nf + 2) * 1024 + cofs0);
      b23[nf][1] = *(const half8v*)(pB + cb + (nf + 2) * 1024 + cofs1);
    }
    if (t + 2 < NT) STG_A(cur, t + 2, 0);
    __builtin_amdgcn_s_barrier();
    asm volatile("s_waitcnt lgkmcnt(0)" ::: "memory");
    __builtin_amdgcn_sched_barrier(0);
    __builtin_amdgcn_s_setprio(1);
#pragma unroll
    for (int mf = 0; mf < 4; ++mf)
#pragma unroll
      for (int nf = 0; nf < 2; ++nf) {
        acc[mf][nf + 2] = __builtin_amdgcn_mfma_f32_16x16x32_f16(af[mf][0], b23[nf][0], acc[mf][nf + 2], 0, 0, 0);
        acc[mf][nf + 2] = __builtin_amdgcn_mfma_f32_16x16x32_f16(af[mf][1], b23[nf][1], acc[mf][nf + 2], 0, 0, 0);
      }
    __builtin_amdgcn_s_setprio(0);
    __builtin_amdgcn_s_barrier();

    // ---------- phase 3: stage A(t+2)h1; tile-boundary wait (counted!); MFMA q3 ----------
    if (t + 2 < NT) STG_A(cur, t + 2, 1);
    if (t < NT - 2) {
      asm volatile("s_waitcnt vmcnt(4)" ::: "memory");   // leave A(t+2)'s 4 loads in flight
    } else if (t == NT - 2) {
      asm volatile("s_waitcnt vmcnt(0)" ::: "memory");   // final drain before last tile
    }
    __builtin_amdgcn_s_barrier();
    __builtin_amdgcn_s_setprio(1);
#pragma unroll
    for (int mf = 4; mf < 8; ++mf)
#pragma unroll
      for (int nf = 0; nf < 2; ++nf) {
        acc[mf][nf + 2] = __builtin_amdgcn_mfma_f32_16x16x32_f16(af[mf][0], b23[nf][0], acc[mf][nf + 2], 0, 0, 0);
        acc[mf][nf + 2] = __builtin_amdgcn_mfma_f32_16x16x32_f16(af[mf][1], b23[nf][1], acc[mf][nf + 2], 0, 0, 0);
      }
    __builtin_amdgcn_s_setprio(0);
    __builtin_amdgcn_s_barrier();
  }

  // ---------- epilogue: bias + online sum-exp + target-logit extract ----------
  // C/D layout: col = l15, row = q*4 + reg (verified convention from prior kernel)
  float bv[4];
#pragma unroll
  for (int nf = 0; nf < 4; ++nf) bv[nf] = bias[n0 + wn + nf * 16 + l15];

#pragma unroll
  for (int mf = 0; mf < 8; ++mf) {
#pragma unroll
    for (int reg = 0; reg < 4; ++reg) {
      const int row = m0 + wm + mf * 16 + q * 4 + reg;
      const int tv = tgt[row];
      float s = 0.f;
#pragma unroll
      for (int nf = 0; nf < 4; ++nf) {
        const float lg = acc[mf][nf][reg] + bv[nf];
        s += __expf(lg);
        if (tv == n0 + wn + nf * 16 + l15) tgtlogit[row] = lg;  // exactly one writer
      }
      s += __shfl_xor(s, 1, 16);
      s += __shfl_xor(s, 2, 16);
      s += __shfl_xor(s, 4, 16);
      s += __shfl_xor(s, 8, 16);
      if (l15 == 0) atomicAdd(&sumexp[row], s);
    }
  }
#undef STG_A
#undef STG_B
}

// ---------------- final DPO reduction (1 block) ----------------
__global__ void dpo_reduce(const float* __restrict__ sumexp, const float* __restrict__ tgtlogit,
                           const int* __restrict__ tgt, float* __restrict__ out) {
  __shared__ float r[8];
  const int tid = threadIdx.x;
  const int j = tid >> 6;
  const int lane = tid & 63;
  const int g = j >> 1, b = j & 1;
  float sum = 0.f;
  for (int s = lane; s < 512; s += 64) {
    const int slot = g * 1024 + b * 512 + s;
    const int tv = tgt[slot & 2047];
    if (tv != -100) sum += tgtlogit[slot] - logf(sumexp[slot]);
  }
#pragma unroll
  for (int m = 1; m < 64; m <<= 1) sum += __shfl_xor(sum, m, 64);
  if (lane == 0) r[j] = sum;
  __syncthreads();
  if (tid == 0) {
    const float beta = 0.1f;
    float pc[2] = {r[0], r[1]}, pr[2] = {r[2], r[3]};
    float rc[2] = {r[4], r[5]}, rr[2] = {r[6], r[7]};
    float loss = 0.f, cr[2], rj[2];
    for (int bb = 0; bb < 2; ++bb) {
      float d = beta * ((pc[bb] - pr[bb]) - (rc[bb] - rr[bb]));
      float ls = fminf(d, 0.f) - log1pf(expf(-fabsf(d)));
      loss += -ls;
      cr[bb] = beta * (pc[bb] - rc[bb]);
      rj[bb] = beta * (pr[bb] - rr[bb]);
    }
    out[0] = loss * 0.5f;
    out[1] = 0.5f * (cr[0] + cr[1]);
    out[2] = 0.5f * (rj[0] + rj[1]);
    out[3] = 0.5f * ((cr[0] - rj[0]) + (cr[1] - rj[1]));
    out[4] = 0.5f * ((cr[0] > rj[0] ? 1.f : 0.f) + (cr[1] > rj[1] ? 1.f : 0.f));
    out[5] = 0.f;
  }
}

extern "C" void kernel_launch(void* const* d_in, const int* in_sizes, int n_in,
                              void* d_out, int out_size, void* d_ws, size_t ws_size,
                              hipStream_t stream) {
  const float* x_c   = (const float*)d_in[0];
  const float* x_r   = (const float*)d_in[1];
  const float* rx_c  = (const float*)d_in[2];
  const float* rx_r  = (const float*)d_in[3];
  const float* Wt    = (const float*)d_in[4];
  const float* bias  = (const float*)d_in[5];
  const float* rWt   = (const float*)d_in[6];
  const float* rbias = (const float*)d_in[7];
  const int*   tc    = (const int*)d_in[8];
  const int*   tr    = (const int*)d_in[9];
  float* out = (float*)d_out;

  // workspace layout (~148 MB): W16 fp16 (reused for both weights) | X16 fp16 | scalars
  char* ws = (char*)d_ws;
  const size_t W16_B = (size_t)VOCAB * DIM_H * 2;
  const size_t X16_B = (size_t)4096 * DIM_H * 2;
  _Float16* W16   = (_Float16*)ws;
  _Float16* X16   = (_Float16*)(ws + W16_B);
  float*    sume  = (float*)(ws + W16_B + X16_B);
  float*    tlog  = (float*)(ws + W16_B + X16_B + 16384);
  int*      tgt   = (int*)  (ws + W16_B + X16_B + 32768);

  hipMemsetAsync(sume, 0, 32768, stream);

  prep<<<72200, 256, 0, stream>>>(x_c, x_r, rx_c, rx_r, Wt, X16, W16, tc, tr, tgt);

  const long nx = 1024L * DIM_H;
  const long nw = (long)VOCAB * DIM_H;

  gemm_lse<<<1000, 512, 0, stream>>>(X16, W16, bias, tgt, sume, tlog);

  cvt_f32_f16<<<(unsigned)(nw / 4 / 256), 256, 0, stream>>>(rWt, W16, nw);
  gemm_lse<<<1000, 512, 0, stream>>>(X16 + 2 * nx, W16, rbias, tgt, sume + 2048, tlog + 2048);

  dpo_reduce<<<1, 512, 0, stream>>>(sume, tlog, tgt, out);
}